// Round 4
// baseline (158.738 us; speedup 1.0000x reference)
//
#include <hip/hip_runtime.h>
#include <stdint.h>

#define N 4096
#define RG 32                 // 32x32 cells of 16 px over 512x512 (r=5 < 16 => 3x3 walk)
#define CAP 24                // bucket capacity; Binom(4096,1/1024) tail ~1e-10
#define ECAP 6144             // expected ~1800 directed edges/class

// monotonic float32 -> uint32 mapping (order-preserving)
__device__ __forceinline__ uint32_t f2s(float f) {
    uint32_t u = __float_as_uint(f);
    return (u & 0x80000000u) ? ~u : (u | 0x80000000u);
}

// ---- K1: softmax, direct outputs (cols 0..2), pts, sort keys, scores ----
__global__ void __launch_bounds__(256)
k_prep(const float* __restrict__ logits, const float* __restrict__ boxes,
       const float* __restrict__ tsz, float* __restrict__ out,
       float2* __restrict__ pts, uint64_t* __restrict__ keys,
       float* __restrict__ scores)
{
    int i = blockIdx.x * 256 + threadIdx.x;
    if (i >= N) return;
    float w = tsz[0], h = tsz[1];
    float x0 = logits[i*3+0], x1 = logits[i*3+1], x2 = logits[i*3+2];
    float mx = fmaxf(x0, fmaxf(x1, x2));
    float e0 = expf(x0 - mx), e1 = expf(x1 - mx), e2 = expf(x2 - mx);
    float sum = e0 + e1 + e2;
    float px = boxes[i*2+0] * w, py = boxes[i*2+1] * h;
    out[i*5+0] = 1.0f - e2 / sum;      // tgt score
    out[i*5+1] = px;                   // x (exact)
    out[i*5+2] = py;                   // y (exact)
    pts[i] = make_float2(px, py);
    float s0 = e0 / sum, s1 = e1 / sum;
    scores[i]     = s0;
    scores[N + i] = s1;
    uint32_t k0 = (s0 >= 0.05f) ? f2s(s0) : 0u;   // invalid sorts last
    uint32_t k1 = (s1 >= 0.05f) ? f2s(s1) : 0u;
    // tie-break: smaller original index first under DESCENDING sort (stable)
    keys[i]     = ((uint64_t)k0 << 32) | (uint32_t)(~(uint32_t)i);
    keys[N + i] = ((uint64_t)k1 << 32) | (uint32_t)(~(uint32_t)i);
}

// ---- K2: rank-by-count (descending slot = #keys strictly greater) ----
// 256 blocks x 256 threads: 32 points/block, 8 threads/point x 512 cmps.
__global__ void __launch_bounds__(256)
k_rank(const uint64_t* __restrict__ keys, uint32_t* __restrict__ ranks)
{
    __shared__ uint64_t sk[N];
    __shared__ uint32_t part[32][8];
    int tid = threadIdx.x;
    int cls = blockIdx.x >> 7;         // 0 or 1
    int seg = blockIdx.x & 127;        // 32-point segment
    const uint64_t* kc = keys + cls * N;
    for (int r = tid; r < N; r += 256) sk[r] = kc[r];
    __syncthreads();
    int pl  = tid & 31;                // point-local
    int sub = tid >> 5;                // 0..7
    uint64_t my = sk[seg*32 + pl];
    int cnt = 0;
    int j0 = sub * (N/8);
    #pragma unroll 4
    for (int j = j0; j < j0 + N/8; ++j) cnt += (sk[j] > my) ? 1 : 0;
    part[pl][sub] = (uint32_t)cnt;
    __syncthreads();
    if (tid < 32) {
        uint32_t r = 0;
        #pragma unroll
        for (int s = 0; s < 8; ++s) r += part[tid][s];
        ranks[cls*N + seg*32 + tid] = r;
    }
}

// ---- K3: per-class fully-LDS resolve: bin -> edges -> Jacobi -> scatter ----
// One block per class. Jacobi fixpoint of
//   keep[v] = valid[v] & !any(u->v edge with keep[u])
// on the rank-DAG converges in <= DAG-depth rounds and equals greedy NMS.
__global__ void __launch_bounds__(1024)
k_resolve(const float2* __restrict__ pts, const uint32_t* __restrict__ ranks,
          const float* __restrict__ scores, float* __restrict__ out)
{
    __shared__ float2   spts[N];            // 32 KB
    __shared__ float    ssc[N];             // 16 KB
    __shared__ uint16_t r16[N];             //  8 KB
    __shared__ uint16_t bkt[RG*RG*CAP];     // 48 KB
    __shared__ uint32_t cnt[RG*RG];         //  4 KB
    __shared__ uint32_t edges[ECAP];        // 24 KB
    __shared__ uint32_t validw[N/32], keepw[N/32], suppw[N/32];
    __shared__ int ecnt, schanged;
    int cls = blockIdx.x, tid = threadIdx.x;

    for (int k = tid; k < N; k += 1024) {
        spts[k] = pts[k];
        ssc[k]  = scores[cls*N + k];
        r16[k]  = (uint16_t)ranks[cls*N + k];
    }
    if (tid < RG*RG) cnt[tid] = 0;          // RG*RG == 1024
    if (tid == 0) ecnt = 0;
    __syncthreads();

    // bin points into 16-px cells (LDS atomics); init valid/keep bitsets
    for (int k = tid; k < N; k += 1024) {
        float2 p = spts[k];
        int cx = min(max((int)(p.x * 0.0625f), 0), RG - 1);
        int cy = min(max((int)(p.y * 0.0625f), 0), RG - 1);
        int c = cy * RG + cx;
        uint32_t pos = atomicAdd(&cnt[c], 1u);
        if (pos < CAP) bkt[c*CAP + pos] = (uint16_t)k;
    }
    if (tid < N/32) {
        uint32_t wbits = 0;
        #pragma unroll
        for (int b = 0; b < 32; ++b)
            if (ssc[tid*32 + b] >= 0.05f) wbits |= 1u << b;
        validw[tid] = wbits; keepw[tid] = wbits;
    }
    __syncthreads();

    // directed edges k->j (rank k < rank j), each unordered pair emitted once
    for (int k = tid; k < N; k += 1024) {
        if (ssc[k] < 0.05f) continue;
        float2 p = spts[k];
        uint16_t myr = r16[k];
        int cx = min(max((int)(p.x * 0.0625f), 0), RG - 1);
        int cy = min(max((int)(p.y * 0.0625f), 0), RG - 1);
        for (int dy = -1; dy <= 1; ++dy) {
            int yy = cy + dy; if (yy < 0 || yy >= RG) continue;
            for (int dx = -1; dx <= 1; ++dx) {
                int xx = cx + dx; if (xx < 0 || xx >= RG) continue;
                int c = yy * RG + xx;
                int n = min((int)cnt[c], CAP);
                for (int t = 0; t < n; ++t) {
                    int j = bkt[c*CAP + t];
                    if (r16[j] <= myr) continue;        // direction + skips j==k
                    if (ssc[j] < 0.05f) continue;
                    float2 q = spts[j];
                    float ddx = __fsub_rn(p.x, q.x);
                    float ddy = __fsub_rn(p.y, q.y);
                    float d2 = __fadd_rn(__fmul_rn(ddx, ddx), __fmul_rn(ddy, ddy));
                    if (d2 < 25.0f) {
                        int pos = atomicAdd(&ecnt, 1);
                        if (pos < ECAP)
                            edges[pos] = ((uint32_t)k << 12) | (uint32_t)j;
                    }
                }
            }
        }
    }
    __syncthreads();
    int ec = min(ecnt, ECAP);

    for (int round = 0; round < N; ++round) {
        if (tid < N/32) suppw[tid] = 0;
        if (tid == 0) schanged = 0;
        __syncthreads();
        for (int k = tid; k < ec; k += 1024) {
            uint32_t e = edges[k];
            int u = e >> 12, v = e & (N - 1);
            if ((keepw[u >> 5] >> (u & 31)) & 1u)
                atomicOr(&suppw[v >> 5], 1u << (v & 31));
        }
        __syncthreads();
        if (tid < N/32) {
            uint32_t nw = validw[tid] & ~suppw[tid];
            if (nw != keepw[tid]) { keepw[tid] = nw; schanged = 1; }
        }
        __syncthreads();
        if (!schanged) break;
    }

    // output per SORTED slot, as in reference
    for (int k = tid; k < N; k += 1024) {
        int slot = r16[k];
        bool kp = (keepw[k >> 5] >> (k & 31)) & 1u;
        out[slot*5 + 3 + cls] = kp ? ssc[k] : 0.0f;
    }
}

extern "C" void kernel_launch(void* const* d_in, const int* in_sizes, int n_in,
                              void* d_out, int out_size, void* d_ws, size_t ws_size,
                              hipStream_t stream) {
    const float* logits = (const float*)d_in[0];  // [1,4096,3]
    const float* boxes  = (const float*)d_in[1];  // [1,4096,2]
    // d_in[2] = pred_gids, unused by the reference
    const float* tsz    = (const float*)d_in[3];  // [1,2]
    float* out = (float*)d_out;                   // [1,4096,5]

    uint8_t* ws = (uint8_t*)d_ws;
    float2*   pts    = (float2*)  ws;             // 32 KB
    uint64_t* keys   = (uint64_t*)(ws + 32768);   // 64 KB (2 classes)
    uint32_t* ranks  = (uint32_t*)(ws + 98304);   // 32 KB
    float*    scores = (float*)   (ws + 131072);  // 32 KB

    hipLaunchKernelGGL(k_prep,    dim3(16),  dim3(256),  0, stream,
                       logits, boxes, tsz, out, pts, keys, scores);
    hipLaunchKernelGGL(k_rank,    dim3(256), dim3(256),  0, stream, keys, ranks);
    hipLaunchKernelGGL(k_resolve, dim3(2),   dim3(1024), 0, stream,
                       pts, ranks, scores, out);
}

// Round 5
// 105.520 us; speedup vs baseline: 1.5043x; 1.5043x over previous
//
#include <hip/hip_runtime.h>
#include <stdint.h>

#define N 4096
#define GRID_DIM 64            // 64x64 cells of 8 px over 512x512 (r=5 < 8 => 3x3 walk)
#define CAP 16                 // bucket capacity (Poisson(1): overflow ~1e-15)
#define ECAP 8192              // directed edges per class (expect ~2000)
#define EBUF 2048              // per-block LDS edge staging

// monotonic float32 -> uint32 mapping (order-preserving)
__device__ __forceinline__ uint32_t f2s(float f) {
    uint32_t u = __float_as_uint(f);
    return (u & 0x80000000u) ? ~u : (u | 0x80000000u);
}

// ---- K1: softmax, direct outputs (cols 0..2), pts, keys, scores, binning ----
__global__ void __launch_bounds__(256)
k_prep(const float* __restrict__ logits, const float* __restrict__ boxes,
       const float* __restrict__ tsz, float* __restrict__ out,
       float2* __restrict__ pts, uint64_t* __restrict__ keys,
       float* __restrict__ scores, uint32_t* __restrict__ cellcnt,
       uint16_t* __restrict__ buckets)
{
    int i = blockIdx.x * 256 + threadIdx.x;
    if (i >= N) return;
    float w = tsz[0], h = tsz[1];
    float x0 = logits[i*3+0], x1 = logits[i*3+1], x2 = logits[i*3+2];
    float mx = fmaxf(x0, fmaxf(x1, x2));
    float e0 = expf(x0 - mx), e1 = expf(x1 - mx), e2 = expf(x2 - mx);
    float sum = e0 + e1 + e2;
    float px = boxes[i*2+0] * w, py = boxes[i*2+1] * h;
    out[i*5+0] = 1.0f - e2 / sum;      // tgt score
    out[i*5+1] = px;                   // x (exact)
    out[i*5+2] = py;                   // y (exact)
    pts[i] = make_float2(px, py);
    float s0 = e0 / sum, s1 = e1 / sum;
    scores[i]     = s0;
    scores[N + i] = s1;
    uint32_t k0 = (s0 >= 0.05f) ? f2s(s0) : 0u;   // invalid sorts last
    uint32_t k1 = (s1 >= 0.05f) ? f2s(s1) : 0u;
    // tie-break: smaller original index first under DESCENDING sort (stable)
    keys[i]     = ((uint64_t)k0 << 32) | (uint32_t)(~(uint32_t)i);
    keys[N + i] = ((uint64_t)k1 << 32) | (uint32_t)(~(uint32_t)i);
    // spatial bin (8 px cells)
    int cx = min(max((int)(px * 0.125f), 0), GRID_DIM - 1);
    int cy = min(max((int)(py * 0.125f), 0), GRID_DIM - 1);
    int c = cy * GRID_DIM + cx;
    uint32_t pos = atomicAdd(&cellcnt[c], 1u);
    if (pos < CAP) buckets[c*CAP + pos] = (uint16_t)i;
}

// ---- K2: fused rank (blocks 0..255) + directed-edge build (blocks 256..271) ----
__global__ void __launch_bounds__(256)
k_mid(const uint64_t* __restrict__ keys, uint32_t* __restrict__ ranks,
      const float2* __restrict__ pts, const uint32_t* __restrict__ cellcnt,
      const uint16_t* __restrict__ buckets, uint32_t* __restrict__ edges0,
      uint32_t* __restrict__ edges1, uint32_t* __restrict__ ecnt)
{
    __shared__ uint64_t sk[N];                 // 32 KB (rank role)
    int tid = threadIdx.x;
    if (blockIdx.x < 256) {
        // ---- rank-by-count: 32 points/block, 8 threads/point x 512 cmps ----
        __shared__ uint32_t part[32][8];
        int cls = blockIdx.x >> 7;             // 0 or 1
        int seg = blockIdx.x & 127;            // 32-point segment
        const uint64_t* kc = keys + cls * N;
        for (int r = tid; r < N; r += 256) sk[r] = kc[r];
        __syncthreads();
        int pl  = tid & 31;
        int sub = tid >> 5;
        uint64_t my = sk[seg*32 + pl];
        int cnt = 0;
        int j0 = sub * (N/8);
        #pragma unroll 4
        for (int j = j0; j < j0 + N/8; ++j) cnt += (sk[j] > my) ? 1 : 0;
        part[pl][sub] = (uint32_t)cnt;
        __syncthreads();
        if (tid < 32) {
            uint32_t r = 0;
            #pragma unroll
            for (int s = 0; s < 8; ++s) r += part[tid][s];
            ranks[cls*N + seg*32 + tid] = r;
        }
    } else {
        // ---- pair walk -> directed valid-valid edges, LDS-staged ----
        __shared__ uint32_t sbuf[2][EBUF];
        __shared__ int scount[2], sbase[2];
        if (tid < 2) scount[tid] = 0;
        __syncthreads();
        const uint32_t VTH = f2s(0.05f);
        int i = (blockIdx.x - 256) * 256 + tid;
        float2 p = pts[i];
        uint64_t ki0 = keys[i], ki1 = keys[N + i];
        bool vi0 = (uint32_t)(ki0 >> 32) >= VTH;
        bool vi1 = (uint32_t)(ki1 >> 32) >= VTH;
        int cx = min(max((int)(p.x * 0.125f), 0), GRID_DIM - 1);
        int cy = min(max((int)(p.y * 0.125f), 0), GRID_DIM - 1);
        if (vi0 || vi1) {
            for (int dy = -1; dy <= 1; ++dy) {
                int yy = cy + dy; if (yy < 0 || yy >= GRID_DIM) continue;
                for (int dx = -1; dx <= 1; ++dx) {
                    int xx = cx + dx; if (xx < 0 || xx >= GRID_DIM) continue;
                    int c = yy * GRID_DIM + xx;
                    int n = min((int)cellcnt[c], CAP);
                    for (int t = 0; t < n; ++t) {
                        int j = buckets[c*CAP + t];
                        if (j <= i) continue;          // each unordered pair once
                        float2 q = pts[j];
                        float ddx = __fsub_rn(p.x, q.x);
                        float ddy = __fsub_rn(p.y, q.y);
                        float d2 = __fadd_rn(__fmul_rn(ddx, ddx), __fmul_rn(ddy, ddy));
                        if (d2 >= 25.0f) continue;
                        uint64_t kj0 = keys[j], kj1 = keys[N + j];
                        if (vi0 && (uint32_t)(kj0 >> 32) >= VTH) {
                            int u = (ki0 > kj0) ? i : j;   // bigger key = earlier
                            int v = i + j - u;
                            int pos = atomicAdd(&scount[0], 1);
                            if (pos < EBUF) sbuf[0][pos] = ((uint32_t)u << 12) | (uint32_t)v;
                        }
                        if (vi1 && (uint32_t)(kj1 >> 32) >= VTH) {
                            int u = (ki1 > kj1) ? i : j;
                            int v = i + j - u;
                            int pos = atomicAdd(&scount[1], 1);
                            if (pos < EBUF) sbuf[1][pos] = ((uint32_t)u << 12) | (uint32_t)v;
                        }
                    }
                }
            }
        }
        __syncthreads();
        if (tid < 2) {
            int cnt = min(scount[tid], EBUF);
            sbase[tid] = (int)atomicAdd(&ecnt[tid], (uint32_t)cnt);
            scount[tid] = cnt;
        }
        __syncthreads();
        for (int k = tid; k < scount[0]; k += 256) {
            int pos = sbase[0] + k;
            if (pos < ECAP) edges0[pos] = sbuf[0][k];
        }
        for (int k = tid; k < scount[1]; k += 256) {
            int pos = sbase[1] + k;
            if (pos < ECAP) edges1[pos] = sbuf[1][k];
        }
    }
}

// ---- K3: per-class Jacobi fixpoint on LDS bitsets + scatter ----
// keep[v] = valid[v] & !any(u->v edge with keep[u]); unique fixpoint on the
// key-ordered DAG == greedy NMS. Converges in <= chain-depth rounds.
__global__ void __launch_bounds__(1024)
k_resolve(const uint32_t* __restrict__ edges0, const uint32_t* __restrict__ edges1,
          const uint32_t* __restrict__ ecnt, const uint32_t* __restrict__ ranks,
          const float* __restrict__ scores, float* __restrict__ out)
{
    __shared__ float    ssc[N];             // 16 KB
    __shared__ uint16_t r16[N];             //  8 KB
    __shared__ uint32_t sedge[ECAP];        // 32 KB
    __shared__ uint32_t validw[N/32], keepw[N/32], suppw[N/32];
    __shared__ int schanged;
    int cls = blockIdx.x, tid = threadIdx.x;
    const uint32_t* eg = cls ? edges1 : edges0;
    int ec = min((int)ecnt[cls], ECAP);

    for (int k = tid; k < N; k += 1024) {
        ssc[k] = scores[cls*N + k];
        r16[k] = (uint16_t)ranks[cls*N + k];
    }
    for (int k = tid; k < ec; k += 1024) sedge[k] = eg[k];
    __syncthreads();
    if (tid < N/32) {
        uint32_t wbits = 0;
        #pragma unroll
        for (int b = 0; b < 32; ++b)
            if (ssc[tid*32 + b] >= 0.05f) wbits |= 1u << b;
        validw[tid] = wbits; keepw[tid] = wbits;
    }
    __syncthreads();

    for (int round = 0; round < N; ++round) {
        if (tid < N/32) suppw[tid] = 0;
        if (tid == 0) schanged = 0;
        __syncthreads();
        for (int k = tid; k < ec; k += 1024) {
            uint32_t e = sedge[k];
            int u = e >> 12, v = e & (N - 1);
            if ((keepw[u >> 5] >> (u & 31)) & 1u)
                atomicOr(&suppw[v >> 5], 1u << (v & 31));
        }
        __syncthreads();
        if (tid < N/32) {
            uint32_t nw = validw[tid] & ~suppw[tid];
            if (nw != keepw[tid]) { keepw[tid] = nw; schanged = 1; }
        }
        __syncthreads();
        if (!schanged) break;
    }

    // output per SORTED slot, as in reference (ranks form a permutation)
    for (int k = tid; k < N; k += 1024) {
        int slot = r16[k];
        bool kp = (keepw[k >> 5] >> (k & 31)) & 1u;
        out[slot*5 + 3 + cls] = kp ? ssc[k] : 0.0f;
    }
}

extern "C" void kernel_launch(void* const* d_in, const int* in_sizes, int n_in,
                              void* d_out, int out_size, void* d_ws, size_t ws_size,
                              hipStream_t stream) {
    const float* logits = (const float*)d_in[0];  // [1,4096,3]
    const float* boxes  = (const float*)d_in[1];  // [1,4096,2]
    // d_in[2] = pred_gids, unused by the reference
    const float* tsz    = (const float*)d_in[3];  // [1,2]
    float* out = (float*)d_out;                   // [1,4096,5]

    uint8_t* ws = (uint8_t*)d_ws;
    uint32_t* ecnts   = (uint32_t*)ws;                        // @0, 2 counters
    uint32_t* cellcnt = (uint32_t*)(ws + 256);                // 16 KB
    uint16_t* buckets = (uint16_t*)(ws + 16640);              // 128 KB
    float2*   pts     = (float2*)  (ws + 147712);             // 32 KB
    uint64_t* keys    = (uint64_t*)(ws + 180480);             // 64 KB (2 cls)
    uint32_t* ranks   = (uint32_t*)(ws + 246016);             // 32 KB
    float*    scores  = (float*)   (ws + 278784);             // 32 KB
    uint32_t* edges0  = (uint32_t*)(ws + 311552);             // 32 KB
    uint32_t* edges1  = (uint32_t*)(ws + 344320);             // 32 KB

    // zero edge counters + cell counts (ws re-poisoned to 0xAA each call)
    hipMemsetAsync(ws, 0, 16640, stream);

    hipLaunchKernelGGL(k_prep,    dim3(16),  dim3(256),  0, stream,
                       logits, boxes, tsz, out, pts, keys, scores, cellcnt, buckets);
    hipLaunchKernelGGL(k_mid,     dim3(272), dim3(256),  0, stream,
                       keys, ranks, pts, cellcnt, buckets, edges0, edges1, ecnts);
    hipLaunchKernelGGL(k_resolve, dim3(2),   dim3(1024), 0, stream,
                       edges0, edges1, ecnts, ranks, scores, out);
}